// Round 11
// baseline (567.038 us; speedup 1.0000x reference)
//
#include <hip/hip_runtime.h>
#include <math.h>

#define NEG_INF (-__builtin_inff())
#define BSHIFT 8                    // 256-node buckets
#define BCAP 6144                   // k_bcsr LDS pair capacity
#define CH 4096                     // edge chunk for bhist/bscatter (4 blocks/CU)

typedef __attribute__((ext_vector_type(8))) short short8;    // 8 bf16 = 4 VGPR
typedef __attribute__((ext_vector_type(4))) float f32x4;

__device__ __forceinline__ float silu_f(float y) {
    return y / (1.f + __expf(-y));
}

// bf16 round-to-nearest-even helpers for split-precision
__device__ __forceinline__ unsigned short f2bh(float x) {
    unsigned int u = __float_as_uint(x);
    u += 0x7fffu + ((u >> 16) & 1u);
    return (unsigned short)(u >> 16);
}
__device__ __forceinline__ float bh2f(unsigned short h) {
    return __uint_as_float(((unsigned int)h) << 16);
}

// ---------------- Bucketed CSR build ----------------

// pass 1: per-block histogram -> saved to global (reused by k_bscatter) + totals
__global__ __launch_bounds__(256)
void k_bhist(const int* __restrict__ ei, int* __restrict__ btot,
             int* __restrict__ bhist, int E, int NB) {
    __shared__ int lh[512];
    int t = threadIdx.x;
    lh[t] = 0; lh[t + 256] = 0;
    __syncthreads();
    int base = blockIdx.x * CH;
    for (int i = t; i < CH; i += 256) {
        int e = base + i;
        if (e < E) atomicAdd(&lh[ei[E + e] >> BSHIFT], 1);
    }
    __syncthreads();
    bhist[blockIdx.x * 512 + t] = lh[t];
    bhist[blockIdx.x * 512 + t + 256] = lh[t + 256];
    if (lh[t]) atomicAdd(&btot[t], lh[t]);
    if (t + 256 < NB && lh[t + 256]) atomicAdd(&btot[t + 256], lh[t + 256]);
}

__global__ __launch_bounds__(256)
void k_bscan(const int* __restrict__ btot, int* __restrict__ bbase,
             int* __restrict__ bcur, int NB, int E) {
    __shared__ int s[512];
    int t = threadIdx.x;
    int v0 = (t < NB) ? btot[t] : 0;
    int v1 = (t + 256 < NB) ? btot[t + 256] : 0;
    s[t] = v0; s[t + 256] = v1;
    __syncthreads();
    for (int st = 1; st < 512; st <<= 1) {
        int a0 = (t >= st) ? s[t - st] : 0;
        int a1 = (t + 256 >= st) ? s[t + 256 - st] : 0;
        __syncthreads();
        s[t] += a0; s[t + 256] += a1;
        __syncthreads();
    }
    if (t < NB)       { bbase[t] = s[t] - v0;             bcur[t] = s[t] - v0; }
    if (t + 256 < NB) { bbase[t + 256] = s[t + 256] - v1; bcur[t + 256] = s[t + 256] - v1; }
    if (t == 0) bbase[NB] = E;
}

// single-pass scatter: histogram reloaded from k_bhist's output
__global__ __launch_bounds__(256)
void k_bscatter(const int* __restrict__ ei, int* __restrict__ bcur,
                const int* __restrict__ bhist,
                int2* __restrict__ pairs, int E, int NB) {
    __shared__ int2 sp[CH];                   // 32 KB staging
    __shared__ int lh[512], lsc[512], lcur[512], gb[512];
    int t = threadIdx.x;
    lh[t] = bhist[blockIdx.x * 512 + t];
    lh[t + 256] = bhist[blockIdx.x * 512 + t + 256];
    lcur[t] = 0; lcur[t + 256] = 0;
    __syncthreads();
    lsc[t] = lh[t]; lsc[t + 256] = lh[t + 256];
    __syncthreads();
    for (int st = 1; st < 512; st <<= 1) {
        int a0 = (t >= st) ? lsc[t - st] : 0;
        int a1 = (t + 256 >= st) ? lsc[t + 256 - st] : 0;
        __syncthreads();
        lsc[t] += a0; lsc[t + 256] += a1;
        __syncthreads();
    }
    int base = blockIdx.x * CH;
    for (int i = t; i < CH; i += 256) {
        int e = base + i;
        if (e < E) {
            int s = ei[e], d = ei[E + e];
            int b = d >> BSHIFT;
            int pos = lsc[b] - lh[b] + atomicAdd(&lcur[b], 1);
            sp[pos] = make_int2(s, d);
        }
    }
    __syncthreads();
    if (t < NB && lh[t]) gb[t] = atomicAdd(&bcur[t], lh[t]);
    if (t + 256 < NB && lh[t + 256]) gb[t + 256] = atomicAdd(&bcur[t + 256], lh[t + 256]);
    __syncthreads();
    int tot = lsc[511];
    for (int i = t; i < tot; i += 256) {
        int2 p = sp[i];
        int b = p.y >> BSHIFT;
        pairs[gb[b] + (i - (lsc[b] - lh[b]))] = p;
    }
}

__global__ __launch_bounds__(256)
void k_bcsr(const int2* __restrict__ pairs, const int* __restrict__ bbase,
            int* __restrict__ csr, int* __restrict__ off, int N, int NB, int E) {
    __shared__ int2 sp[BCAP];
    __shared__ int lh[256], lsc[256], lcur[256];
    int t = threadIdx.x;
    int b = blockIdx.x;
    int base = bbase[b];
    int m = bbase[b + 1] - base;
    int v0 = b << BSHIFT;
    lh[t] = 0; lcur[t] = 0;
    __syncthreads();
    bool fits = (m <= BCAP);
    for (int i = t; i < m; i += 256) {
        int2 p = pairs[base + i];
        if (fits) sp[i] = p;
        atomicAdd(&lh[p.y & 255], 1);
    }
    __syncthreads();
    int myv = lh[t];
    lsc[t] = myv;
    __syncthreads();
    for (int st = 1; st < 256; st <<= 1) {
        int a = (t >= st) ? lsc[t - st] : 0;
        __syncthreads();
        lsc[t] += a;
        __syncthreads();
    }
    int excl = lsc[t] - myv;
    __syncthreads();
    lsc[t] = excl;
    __syncthreads();
    int v = v0 + t;
    if (v < N) off[v] = base + excl;
    if (b == NB - 1 && t == 0) off[N] = E;
    for (int i = t; i < m; i += 256) {
        int2 p = fits ? sp[i] : pairs[base + i];
        int d = p.y & 255;
        int pos = lsc[d] + atomicAdd(&lcur[d], 1);
        csr[base + pos] = p.x;
    }
}

// ---------------- Prep: fragment-packed weights (bf16 hi/lo) ----------------
// b=0: mlp W1   b=1: mlp g*W2   b=2: k12   b=3..5: sage layer b-3

__global__ void k_prep(const float* __restrict__ mW1, const float* __restrict__ mg,
                       const float* __restrict__ mbn, const float* __restrict__ mW2,
                       const float* __restrict__ mb2,
                       const float* __restrict__ Wl, const float* __restrict__ Wr,
                       unsigned short* __restrict__ w1fh, unsigned short* __restrict__ w1fl,
                       unsigned short* __restrict__ w2fh, unsigned short* __restrict__ w2fl,
                       unsigned short* __restrict__ wsfh, unsigned short* __restrict__ wsfl,
                       float* __restrict__ k12)
{
    int b = blockIdx.x, t = threadIdx.x;
    if (b == 0) {
        for (int idx = t; idx < 2048; idx += 256) {
            int nt = idx >> 7, rem = idx & 127;
            int kc = rem >> 6, ln = rem & 63;
#pragma unroll
            for (int i = 0; i < 8; ++i) {
                int c = kc * 32 + (ln >> 4) * 8 + i;
                int j = nt * 16 + (ln & 15);
                float v = mW1[c * 256 + j];
                unsigned short hi = f2bh(v);
                w1fh[idx * 8 + i] = hi;
                w1fl[idx * 8 + i] = f2bh(v - bh2f(hi));
            }
        }
    } else if (b == 1) {
        for (int idx = t; idx < 2048; idx += 256) {
            int nt2 = idx >> 9, rem = idx & 511;
            int kc2 = rem >> 6, ln = rem & 63;
#pragma unroll
            for (int i = 0; i < 8; ++i) {
                int j = kc2 * 32 + (ln >> 4) * 8 + i;
                int o = nt2 * 16 + (ln & 15);
                float v = mg[j] * mW2[j * 64 + o];
                unsigned short hi = f2bh(v);
                w2fh[idx * 8 + i] = hi;
                w2fl[idx * 8 + i] = f2bh(v - bh2f(hi));
            }
        }
    } else if (b == 2 && t < 64) {
        float a1 = 0.f, a2 = 0.f;
        for (int j = 0; j < 256; ++j) {
            a1 += mbn[j] * mW2[j * 64 + t];
            a2 += mg[j]  * mW2[j * 64 + t];
        }
        k12[t] = a1 + mb2[t];
        k12[64 + t] = a2;
    } else if (b >= 3 && b < 6) {
        int l = b - 3;
        for (int idx = t; idx < 1536; idx += 256) {
            int tile = idx >> 6, ln = idx & 63;
            int nt = tile / 6, kc = tile % 6;
#pragma unroll
            for (int i = 0; i < 8; ++i) {
                int k = kc * 32 + (ln >> 4) * 8 + i;
                int o = nt * 16 + (ln & 15);
                float v = (k < 128) ? Wl[((l * 128) + k) * 64 + o]
                                    : Wr[((l * 64) + (k - 128)) * 64 + o];
                unsigned short hi = f2bh(v);
                wsfh[((l * 24 + tile) * 64 + ln) * 8 + i] = hi;
                wsfl[((l * 24 + tile) * 64 + ln) * 8 + i] = f2bh(v - bh2f(hi));
            }
        }
    }
}

// ---------------- Layer 0 (N_IN=4), one thread per node, 8-deep batches ----------------

__global__ __launch_bounds__(256, 4)
void k_layer0(const float* __restrict__ x, float* __restrict__ hout,
              const int* __restrict__ off, const int* __restrict__ csr,
              const float* __restrict__ Wl0, const float* __restrict__ bl0,
              const float* __restrict__ Wr0, const float* __restrict__ Wres,
              const float* __restrict__ bres, const float* __restrict__ lg,
              const float* __restrict__ lb, int N)
{
    __shared__ float sWl[512], sWr[256], sWres[256], sC[256];
    int t = threadIdx.x;
    sWl[t] = Wl0[t]; sWl[256 + t] = Wl0[256 + t];
    sWr[t] = Wr0[t];
    sWres[t] = Wres[t];
    if (t < 64) { sC[t] = bl0[t]; sC[64 + t] = bres[t]; sC[128 + t] = lg[t]; sC[192 + t] = lb[t]; }
    __syncthreads();
    int v = blockIdx.x * 256 + t;
    if (v >= N) return;
    const float4* X4 = reinterpret_cast<const float4*>(x);
    float4 xv = X4[v];
    int s0 = off[v], s1 = off[v + 1];
    int deg = s1 - s0;
    float4 mx = {NEG_INF, NEG_INF, NEG_INF, NEG_INF};
    float4 sm = {0.f, 0.f, 0.f, 0.f};
    for (int e = s0; e < s1; e += 8) {
        int last = s1 - 1;
        float4 a[8];
#pragma unroll
        for (int u = 0; u < 8; ++u) a[u] = X4[csr[min(e + u, last)]];
#pragma unroll
        for (int u = 0; u < 8; ++u) {
            mx.x = fmaxf(mx.x, a[u].x); mx.y = fmaxf(mx.y, a[u].y);
            mx.z = fmaxf(mx.z, a[u].z); mx.w = fmaxf(mx.w, a[u].w);
            sm.x += a[u].x; sm.y += a[u].y; sm.z += a[u].z; sm.w += a[u].w;
        }
    }
    float4 mn;
    if (deg == 0) {
        mx.x = 0.f; mx.y = 0.f; mx.z = 0.f; mx.w = 0.f;
        mn.x = 0.f; mn.y = 0.f; mn.z = 0.f; mn.w = 0.f;
    } else {
        int npad = (((deg + 7) >> 3) << 3) - deg;        // dups all clamp to csr[s1-1]
        float4 xl = X4[csr[s1 - 1]];                      // L1-hot
        float fp = (float)npad, inv = 1.f / (float)deg;
        mn.x = (sm.x - fp * xl.x) * inv; mn.y = (sm.y - fp * xl.y) * inv;
        mn.z = (sm.z - fp * xl.z) * inv; mn.w = (sm.w - fp * xl.w) * inv;
    }
    float a[64];
    float acc1 = 0.f, acc2 = 0.f;
#pragma unroll
    for (int k = 0; k < 64; ++k) {
        float tv = sC[k]
            + mx.x * sWl[k]       + mx.y * sWl[64 + k]  + mx.z * sWl[128 + k] + mx.w * sWl[192 + k]
            + mn.x * sWl[256 + k] + mn.y * sWl[320 + k] + mn.z * sWl[384 + k] + mn.w * sWl[448 + k]
            + xv.x * sWr[k]       + xv.y * sWr[64 + k]  + xv.z * sWr[128 + k] + xv.w * sWr[192 + k];
        a[k] = tv; acc1 += tv; acc2 += tv * tv;
    }
    float mu = acc1 * (1.f / 64.f);
    float var = acc2 * (1.f / 64.f) - mu * mu;
    float rs = rsqrtf(var + 1e-5f);
    float* orow = hout + (size_t)v * 64;
#pragma unroll
    for (int k = 0; k < 64; ++k) {
        float res = sC[64 + k] + xv.x * sWres[k] + xv.y * sWres[64 + k]
                  + xv.z * sWres[128 + k] + xv.w * sWres[192 + k];
        float y = (a[k] - mu) * rs * sC[128 + k] + sC[192 + k] + res;
        orow[k] = silu_f(y);
    }
}

// ---------------- k_agg: gather + aggregate, pipelined next-node prefetch ----------------

__global__ __launch_bounds__(256, 8)
void k_agg(const float* __restrict__ hin, float* __restrict__ aggws,
           const int* __restrict__ off, const int* __restrict__ csr, int N)
{
    int lane = threadIdx.x & 63;
    int gw = (blockIdx.x * blockDim.x + threadIdx.x) >> 6;
    int nw = (gridDim.x * blockDim.x) >> 6;
    int v = gw;
    if (v >= N) return;
    int s0 = off[v], s1 = off[v + 1];
    int idxv = (s1 > s0) ? csr[min(s0 + lane, s1 - 1)] : 0;
    while (v < N) {
        // prefetch next node's index chain (hidden behind this node's gathers)
        int nv = v + nw;
        int ns0 = 0, ns1 = 0, nidxv = 0;
        if (nv < N) {
            ns0 = off[nv]; ns1 = off[nv + 1];
            nidxv = (ns1 > ns0) ? csr[min(ns0 + lane, ns1 - 1)] : 0;
        }
        int deg = s1 - s0;
        float mx = NEG_INF, sm = 0.f;
        int npad = 0;
        for (int cb = s0; cb < s1; cb += 64) {
            int cdeg = min(64, s1 - cb);
            int iv = (cb == s0) ? idxv : csr[min(cb + lane, s1 - 1)];
            for (int b = 0; b < cdeg; b += 16) {
                float vv[16];
#pragma unroll
                for (int u = 0; u < 16; ++u) {
                    int iu = __builtin_amdgcn_readlane(iv, b + u);   // b+u <= 63
                    vv[u] = hin[((size_t)iu << 6) + lane];
                }
#pragma unroll
                for (int u = 0; u < 16; ++u) { mx = fmaxf(mx, vv[u]); sm += vv[u]; }
            }
            npad += (((cdeg + 15) >> 4) << 4) - cdeg;   // dup lanes all clamp to csr[s1-1]
        }
        float mean;
        if (deg == 0) { mx = 0.f; mean = 0.f; }
        else {
            float hl = hin[((size_t)csr[s1 - 1] << 6) + lane];   // L1-hot
            mean = (sm - (float)npad * hl) / (float)deg;
        }
        aggws[((size_t)v << 7) + lane] = mx;
        aggws[((size_t)v << 7) + 64 + lane] = mean;
        v = nv; s0 = ns0; s1 = ns1; idxv = nidxv;
    }
}

// ---------------- k_smm_d: LDS-free MFMA SAGE matmul+LN+silu (round-10, proven) ----------------

__global__ __launch_bounds__(256, 4)
void k_smm_d(const float* __restrict__ aggws, const float* __restrict__ hin,
             float* __restrict__ hout,
             const unsigned short* __restrict__ wfh, const unsigned short* __restrict__ wfl,
             const float* __restrict__ bl, const float* __restrict__ lg,
             const float* __restrict__ lb, int N)
{
    int t = threadIdx.x;
    int lane = t & 63, w = t >> 6, quad = lane >> 4, l15 = lane & 15;
    int nodebase = (blockIdx.x * 4 + w) * 16;
    if (nodebase >= N) return;
    int arow = min(nodebase + l15, N - 1);

    short8 ah[6], al[6];
#pragma unroll
    for (int kc = 0; kc < 6; ++kc) {
        const float* src = (kc < 4)
            ? (aggws + ((size_t)arow << 7) + kc * 32 + quad * 8)
            : (hin + ((size_t)arow << 6) + (kc - 4) * 32 + quad * 8);
        float4 f0 = *(const float4*)(src);
        float4 f1 = *(const float4*)(src + 4);
        float vv[8] = {f0.x, f0.y, f0.z, f0.w, f1.x, f1.y, f1.z, f1.w};
#pragma unroll
        for (int i = 0; i < 8; ++i) {
            unsigned short hi = f2bh(vv[i]);
            ah[kc][i] = (short)hi;
            al[kc][i] = (short)f2bh(vv[i] - bh2f(hi));
        }
    }

    f32x4 acc[4];
#pragma unroll
    for (int nt = 0; nt < 4; ++nt) acc[nt] = (f32x4){0.f, 0.f, 0.f, 0.f};
#pragma unroll
    for (int kc = 0; kc < 6; ++kc) {
#pragma unroll
        for (int nt = 0; nt < 4; ++nt) {
            int fo = ((nt * 6 + kc) * 64 + lane) * 8;
            short8 bh_ = *(const short8*)(wfh + fo);
            short8 bl_ = *(const short8*)(wfl + fo);
            acc[nt] = __builtin_amdgcn_mfma_f32_16x16x32_bf16(ah[kc], bh_, acc[nt], 0, 0, 0);
            acc[nt] = __builtin_amdgcn_mfma_f32_16x16x32_bf16(al[kc], bh_, acc[nt], 0, 0, 0);
            acc[nt] = __builtin_amdgcn_mfma_f32_16x16x32_bf16(ah[kc], bl_, acc[nt], 0, 0, 0);
        }
    }

    float blv[4], gv[4], bv[4];
#pragma unroll
    for (int nt = 0; nt < 4; ++nt) {
        int ch = nt * 16 + l15;
        blv[nt] = bl[ch]; gv[nt] = lg[ch]; bv[nt] = lb[ch];
    }
    float ps[4], pq[4];
#pragma unroll
    for (int r = 0; r < 4; ++r) { ps[r] = 0.f; pq[r] = 0.f; }
#pragma unroll
    for (int nt = 0; nt < 4; ++nt)
#pragma unroll
        for (int r = 0; r < 4; ++r) {
            float tv = acc[nt][r] + blv[nt];
            acc[nt][r] = tv;
            ps[r] += tv; pq[r] += tv * tv;
        }
#pragma unroll
    for (int r = 0; r < 4; ++r) {
        float a = ps[r], b = pq[r];
#pragma unroll
        for (int m = 1; m < 16; m <<= 1) {
            a += __shfl_xor(a, m, 64);
            b += __shfl_xor(b, m, 64);
        }
        ps[r] = a; pq[r] = b;
    }
#pragma unroll
    for (int r = 0; r < 4; ++r) {
        int node = nodebase + quad * 4 + r;
        float mu = ps[r] * (1.f / 64.f);
        float var = pq[r] * (1.f / 64.f) - mu * mu;
        float rs = rsqrtf(var + 1e-5f);
        if (node < N) {
#pragma unroll
            for (int nt = 0; nt < 4; ++nt) {
                float hs = hin[(size_t)node * 64 + nt * 16 + l15];   // L2-hot
                float y = (acc[nt][r] - mu) * rs * gv[nt] + bv[nt] + hs;
                hout[(size_t)node * 64 + nt * 16 + l15] = silu_f(y);
            }
        }
    }
}

// ---------------- k_mlpm: MFMA MLP (round-7, proven) ----------------

__global__ __launch_bounds__(256, 2)
void k_mlpm(const float* __restrict__ hin, float* __restrict__ hout,
            const unsigned short* __restrict__ w1fh, const unsigned short* __restrict__ w1fl,
            const unsigned short* __restrict__ w2fh, const unsigned short* __restrict__ w2fl,
            const float* __restrict__ b1, const float* __restrict__ K12, int N)
{
    __shared__ __align__(16) char lds[70656];
    float* p1 = (float*)lds;
    float* p2 = (float*)(lds + 1024);
    unsigned short* hhi = (unsigned short*)(lds + 2048);
    unsigned short* hlo = (unsigned short*)(lds + 11264);
    unsigned int* spack = (unsigned int*)(lds + 2048);

    int t = threadIdx.x;
    int lane = t & 63, w = t >> 6, quad = lane >> 4, l15 = lane & 15;

    {
        int row = t >> 2, cq = (t & 3) * 16;
        int node0 = blockIdx.x * 64 + row;
        const float4* hr = (const float4*)(hin + (size_t)min(node0, N - 1) * 64 + cq);
        float v[16];
#pragma unroll
        for (int k = 0; k < 4; ++k) {
            float4 f = hr[k];
            v[4 * k] = f.x; v[4 * k + 1] = f.y; v[4 * k + 2] = f.z; v[4 * k + 3] = f.w;
        }
#pragma unroll
        for (int g = 0; g < 2; ++g) {
            short8 ph, pl;
#pragma unroll
            for (int i = 0; i < 8; ++i) {
                float x = v[g * 8 + i];
                unsigned short hi = f2bh(x);
                ph[i] = (short)hi;
                pl[i] = (short)f2bh(x - bh2f(hi));
            }
            int idx = row * 72 + cq + g * 8;
            *(short8*)(hhi + idx) = ph;
            *(short8*)(hlo + idx) = pl;
        }
    }
    __syncthreads();

    f32x4 acc[4][4];
#pragma unroll
    for (int mt = 0; mt < 4; ++mt)
#pragma unroll
        for (int nt = 0; nt < 4; ++nt)
            acc[mt][nt] = (f32x4){0.f, 0.f, 0.f, 0.f};
#pragma unroll
    for (int kc = 0; kc < 2; ++kc) {
        short8 ah[4], al[4];
#pragma unroll
        for (int mt = 0; mt < 4; ++mt) {
            int idx = (mt * 16 + l15) * 72 + kc * 32 + quad * 8;
            ah[mt] = *(const short8*)(hhi + idx);
            al[mt] = *(const short8*)(hlo + idx);
        }
#pragma unroll
        for (int nt = 0; nt < 4; ++nt) {
            int fo = (((w * 4 + nt) * 2 + kc) * 64 + lane) * 8;
            short8 bh_ = *(const short8*)(w1fh + fo);
            short8 bl_ = *(const short8*)(w1fl + fo);
#pragma unroll
            for (int mt = 0; mt < 4; ++mt) {
                acc[mt][nt] = __builtin_amdgcn_mfma_f32_16x16x32_bf16(ah[mt], bh_, acc[mt][nt], 0, 0, 0);
                acc[mt][nt] = __builtin_amdgcn_mfma_f32_16x16x32_bf16(al[mt], bh_, acc[mt][nt], 0, 0, 0);
                acc[mt][nt] = __builtin_amdgcn_mfma_f32_16x16x32_bf16(ah[mt], bl_, acc[mt][nt], 0, 0, 0);
            }
        }
    }

    float b1v[4];
#pragma unroll
    for (int nt = 0; nt < 4; ++nt) b1v[nt] = b1[(w * 4 + nt) * 16 + l15];
    float psum[4][4], psq[4][4];
#pragma unroll
    for (int mt = 0; mt < 4; ++mt)
#pragma unroll
        for (int r = 0; r < 4; ++r) { psum[mt][r] = 0.f; psq[mt][r] = 0.f; }
#pragma unroll
    for (int mt = 0; mt < 4; ++mt)
#pragma unroll
        for (int nt = 0; nt < 4; ++nt)
#pragma unroll
            for (int r = 0; r < 4; ++r) {
                float sv = silu_f(acc[mt][nt][r] + b1v[nt]);
                acc[mt][nt][r] = sv;
                psum[mt][r] += sv;
                psq[mt][r] += sv * sv;
            }
#pragma unroll
    for (int mt = 0; mt < 4; ++mt)
#pragma unroll
        for (int r = 0; r < 4; ++r) {
            float a = psum[mt][r], b = psq[mt][r];
#pragma unroll
            for (int m = 1; m < 16; m <<= 1) {
                a += __shfl_xor(a, m, 64);
                b += __shfl_xor(b, m, 64);
            }
            psum[mt][r] = a; psq[mt][r] = b;
        }
    if (l15 == 0) {
#pragma unroll
        for (int mt = 0; mt < 4; ++mt)
#pragma unroll
            for (int r = 0; r < 4; ++r) {
                int nl = mt * 16 + quad * 4 + r;
                p1[w * 64 + nl] = psum[mt][r];
                p2[w * 64 + nl] = psq[mt][r];
            }
    }
    __syncthreads();

#pragma unroll
    for (int mt = 0; mt < 4; ++mt)
#pragma unroll
        for (int nt = 0; nt < 4; ++nt)
#pragma unroll
            for (int r = 0; r < 4; ++r) {
                float sv = acc[mt][nt][r];
                unsigned short hi = f2bh(sv);
                unsigned short lo = f2bh(sv - bh2f(hi));
                spack[(mt * 16 + quad * 4 + r) * 268 + (w * 4 + nt) * 16 + l15] =
                    (((unsigned int)hi) << 16) | (unsigned int)lo;
            }
    __syncthreads();

    f32x4 acc2[4];
#pragma unroll
    for (int nt2 = 0; nt2 < 4; ++nt2) acc2[nt2] = (f32x4){0.f, 0.f, 0.f, 0.f};
#pragma unroll
    for (int kc2 = 0; kc2 < 8; ++kc2) {
        int base = (w * 16 + l15) * 268 + kc2 * 32 + quad * 8;
        uint4 q0 = *(const uint4*)(spack + base);
        uint4 q1 = *(const uint4*)(spack + base + 4);
        unsigned int vv[8] = {q0.x, q0.y, q0.z, q0.w, q1.x, q1.y, q1.z, q1.w};
        short8 ah, al;
#pragma unroll
        for (int i = 0; i < 8; ++i) {
            ah[i] = (short)(vv[i] >> 16);
            al[i] = (short)(vv[i] & 0xffffu);
        }
#pragma unroll
        for (int nt2 = 0; nt2 < 4; ++nt2) {
            int fo = ((nt2 * 8 + kc2) * 64 + lane) * 8;
            short8 bh_ = *(const short8*)(w2fh + fo);
            short8 bl_ = *(const short8*)(w2fl + fo);
            acc2[nt2] = __builtin_amdgcn_mfma_f32_16x16x32_bf16(ah, bh_, acc2[nt2], 0, 0, 0);
            acc2[nt2] = __builtin_amdgcn_mfma_f32_16x16x32_bf16(al, bh_, acc2[nt2], 0, 0, 0);
            acc2[nt2] = __builtin_amdgcn_mfma_f32_16x16x32_bf16(ah, bl_, acc2[nt2], 0, 0, 0);
        }
    }

    float k1v[4], k2v[4];
#pragma unroll
    for (int nt2 = 0; nt2 < 4; ++nt2) {
        k1v[nt2] = K12[nt2 * 16 + l15];
        k2v[nt2] = K12[64 + nt2 * 16 + l15];
    }
#pragma unroll
    for (int r = 0; r < 4; ++r) {
        int nl = w * 16 + quad * 4 + r;
        float s1 = p1[nl] + p1[64 + nl] + p1[128 + nl] + p1[192 + nl];
        float s2 = p2[nl] + p2[64 + nl] + p2[128 + nl] + p2[192 + nl];
        float mu = s1 * (1.f / 256.f);
        float var = s2 * (1.f / 256.f) - mu * mu;
        float rs = rsqrtf(var + 1e-5f);
        float rm = rs * mu;
        int node = blockIdx.x * 64 + nl;
        if (node < N) {
#pragma unroll
            for (int nt2 = 0; nt2 < 4; ++nt2)
                hout[(size_t)node * 64 + nt2 * 16 + l15] =
                    rs * acc2[nt2][r] + k1v[nt2] - rm * k2v[nt2];
        }
    }
}

// ---------------- Readout: block per graph ----------------

__global__ __launch_bounds__(256, 2)
void k_readout(const float* __restrict__ h2, const float* __restrict__ x,
               const int* __restrict__ ptr,
               const float* __restrict__ W1, const float* __restrict__ b1,
               const float* __restrict__ lg, const float* __restrict__ lb,
               const float* __restrict__ W2, const float* __restrict__ b2,
               float* __restrict__ out)
{
    __shared__ float f[196];
    __shared__ float sred[4][64];
    __shared__ float mred[4][64];
    __shared__ float lred[8];
    __shared__ float pr[4][4];
    int t = threadIdx.x, lane = t & 63, w = t >> 6;
    int g = blockIdx.x;
    int s0 = ptr[g], s1 = ptr[g + 1];
    float sm = 0.f, mx = NEG_INF;
    for (int r = s0 + w; r < s1; r += 4) {
        float v = h2[(size_t)r * 64 + lane];
        sm += v; mx = fmaxf(mx, v);
    }
    sred[w][lane] = sm; mred[w][lane] = mx;
    __syncthreads();
    if (w == 0) {
        float ssum = sred[0][lane] + sred[1][lane] + sred[2][lane] + sred[3][lane];
        float smax = fmaxf(fmaxf(mred[0][lane], mred[1][lane]),
                           fmaxf(mred[2][lane], mred[3][lane]));
        int cnt = s1 - s0;
        if (cnt == 0) smax = 0.f;
        f[lane] = ssum / (float)max(cnt, 1);
        f[64 + lane] = smax;
        f[128 + lane] = ssum;
    }
    if (t < 4) f[192 + t] = x[(size_t)s0 * 4 + t];
    __syncthreads();
    float o = b1[t];
    for (int c = 0; c < 196; ++c) o += f[c] * W1[c * 256 + t];
    o = silu_f(o);
    float s = o, s2v = o * o;
#pragma unroll
    for (int m = 1; m < 64; m <<= 1) { s += __shfl_xor(s, m, 64); s2v += __shfl_xor(s2v, m, 64); }
    if (lane == 0) { lred[w] = s; lred[4 + w] = s2v; }
    __syncthreads();
    float tot = lred[0] + lred[1] + lred[2] + lred[3];
    float tot2 = lred[4] + lred[5] + lred[6] + lred[7];
    float mu = tot * (1.f / 256.f);
    float var = tot2 * (1.f / 256.f) - mu * mu;
    float u = (o - mu) * rsqrtf(var + 1e-5f) * lg[t] + lb[t];
    float4 w2r = reinterpret_cast<const float4*>(W2)[t];
    float p0 = u * w2r.x, p1 = u * w2r.y, p2 = u * w2r.z, p3 = u * w2r.w;
#pragma unroll
    for (int m = 1; m < 64; m <<= 1) {
        p0 += __shfl_xor(p0, m, 64); p1 += __shfl_xor(p1, m, 64);
        p2 += __shfl_xor(p2, m, 64); p3 += __shfl_xor(p3, m, 64);
    }
    if (lane == 0) { pr[w][0] = p0; pr[w][1] = p1; pr[w][2] = p2; pr[w][3] = p3; }
    __syncthreads();
    if (t < 4) out[g * 4 + t] = pr[0][t] + pr[1][t] + pr[2][t] + pr[3][t] + b2[t];
}

// ---------------- launch ----------------

extern "C" void kernel_launch(void* const* d_in, const int* in_sizes, int n_in,
                              void* d_out, int out_size, void* d_ws, size_t ws_size,
                              hipStream_t stream)
{
    const float* x    = (const float*)d_in[0];
    const int*   ei   = (const int*)d_in[1];
    const int*   ptr  = (const int*)d_in[3];
    const float* Wl0  = (const float*)d_in[4];
    const float* bl0  = (const float*)d_in[5];
    const float* Wr0  = (const float*)d_in[6];
    const float* Wl   = (const float*)d_in[7];
    const float* bl   = (const float*)d_in[8];
    const float* Wr   = (const float*)d_in[9];
    const float* Wres = (const float*)d_in[10];
    const float* bres = (const float*)d_in[11];
    const float* lng  = (const float*)d_in[12];
    const float* lnb  = (const float*)d_in[13];
    const float* mW1  = (const float*)d_in[14];
    const float* mb1  = (const float*)d_in[15];
    const float* mg   = (const float*)d_in[16];
    const float* mbn  = (const float*)d_in[17];
    const float* mW2  = (const float*)d_in[18];
    const float* mb2  = (const float*)d_in[19];
    const float* rW1  = (const float*)d_in[20];
    const float* rb1  = (const float*)d_in[21];
    const float* rg   = (const float*)d_in[22];
    const float* rbn  = (const float*)d_in[23];
    const float* rW2  = (const float*)d_in[24];
    const float* rb2  = (const float*)d_in[25];
    float* out = (float*)d_out;

    int N = in_sizes[0] / 4;
    int E = in_sizes[1] / 2;
    int NG = in_sizes[3] - 1;
    int nchunk = (N + 255) / 256;
    int nblkm  = (N + 63) / 64;
    int NB     = (N + 255) >> BSHIFT;
    int nbh    = (E + CH - 1) / CH;

    char* ws = (char*)d_ws;
    size_t o = 0;
    auto alloc = [&](size_t bytes) -> void* {
        void* p = ws + o;
        o += (bytes + 255) & ~(size_t)255;
        return p;
    };
    int*   off   = (int*)alloc((size_t)(N + 1) * 4);
    int*   btot  = (int*)alloc((size_t)NB * 4);
    int*   bbase = (int*)alloc((size_t)(NB + 1) * 4);
    int*   bcur  = (int*)alloc((size_t)NB * 4);
    int*   bhist = (int*)alloc((size_t)nbh * 512 * 4);
    int*   csr   = (int*)alloc((size_t)E * 4);
    int2*  pairs = (int2*)alloc((size_t)E * 8);
    float* ha    = (float*)alloc((size_t)N * 64 * 4);
    float* hb    = (float*)alloc((size_t)N * 64 * 4);
    float* aggws = (float*)alloc((size_t)N * 128 * 4);
    unsigned short* w1fh = (unsigned short*)alloc(16384 * 2);
    unsigned short* w1fl = (unsigned short*)alloc(16384 * 2);
    unsigned short* w2fh = (unsigned short*)alloc(16384 * 2);
    unsigned short* w2fl = (unsigned short*)alloc(16384 * 2);
    unsigned short* wsfh = (unsigned short*)alloc(36864 * 2);
    unsigned short* wsfl = (unsigned short*)alloc(36864 * 2);
    float* k12   = (float*)alloc(128 * 4);

    hipMemsetAsync(btot, 0, (size_t)NB * 4, stream);
    k_prep<<<6, 256, 0, stream>>>(mW1, mg, mbn, mW2, mb2, Wl, Wr,
                                  w1fh, w1fl, w2fh, w2fl, wsfh, wsfl, k12);
    k_bhist<<<nbh, 256, 0, stream>>>(ei, btot, bhist, E, NB);
    k_bscan<<<1, 256, 0, stream>>>(btot, bbase, bcur, NB, E);
    k_bscatter<<<nbh, 256, 0, stream>>>(ei, bcur, bhist, pairs, E, NB);
    k_bcsr<<<NB, 256, 0, stream>>>(pairs, bbase, csr, off, N, NB, E);

    k_layer0<<<nchunk, 256, 0, stream>>>(x, ha, off, csr, Wl0, bl0, Wr0, Wres, bres, lng, lnb, N);

    k_agg<<<2048, 256, 0, stream>>>(ha, aggws, off, csr, N);
    k_smm_d<<<nblkm, 256, 0, stream>>>(aggws, ha, hb, wsfh,               wsfl,               bl,       lng + 64,  lnb + 64,  N);
    k_agg<<<2048, 256, 0, stream>>>(hb, aggws, off, csr, N);
    k_smm_d<<<nblkm, 256, 0, stream>>>(aggws, hb, ha, wsfh + 24 * 64 * 8, wsfl + 24 * 64 * 8, bl + 64,  lng + 128, lnb + 128, N);
    k_agg<<<2048, 256, 0, stream>>>(ha, aggws, off, csr, N);
    k_smm_d<<<nblkm, 256, 0, stream>>>(aggws, ha, hb, wsfh + 48 * 64 * 8, wsfl + 48 * 64 * 8, bl + 128, lng + 192, lnb + 192, N);

    k_mlpm<<<nblkm, 256, 0, stream>>>(hb, ha, w1fh, w1fl, w2fh, w2fl, mb1, k12, N);
    k_readout<<<NG, 256, 0, stream>>>(ha, x, ptr, rW1, rb1, rg, rbn, rW2, rb2, out);
}

// Round 12
// 562.099 us; speedup vs baseline: 1.0088x; 1.0088x over previous
//
#include <hip/hip_runtime.h>
#include <math.h>

#define NEG_INF (-__builtin_inff())
#define BSHIFT 8                    // 256-node buckets
#define BCAP 6144                   // k_bcsr LDS pair capacity
#define CH 4096                     // edge chunk for bhist/bscatter (4 blocks/CU)

typedef __attribute__((ext_vector_type(8))) short short8;    // 8 bf16 = 4 VGPR
typedef __attribute__((ext_vector_type(4))) float f32x4;

__device__ __forceinline__ float silu_f(float y) {
    return y / (1.f + __expf(-y));
}

// bf16 round-to-nearest-even helpers for split-precision
__device__ __forceinline__ unsigned short f2bh(float x) {
    unsigned int u = __float_as_uint(x);
    u += 0x7fffu + ((u >> 16) & 1u);
    return (unsigned short)(u >> 16);
}
__device__ __forceinline__ float bh2f(unsigned short h) {
    return __uint_as_float(((unsigned int)h) << 16);
}

// ---------------- Bucketed CSR build ----------------

__global__ __launch_bounds__(256)
void k_bhist(const int* __restrict__ ei, int* __restrict__ btot,
             int* __restrict__ bhist, int E, int NB) {
    __shared__ int lh[512];
    int t = threadIdx.x;
    lh[t] = 0; lh[t + 256] = 0;
    __syncthreads();
    int base = blockIdx.x * CH;
    for (int i = t; i < CH; i += 256) {
        int e = base + i;
        if (e < E) atomicAdd(&lh[ei[E + e] >> BSHIFT], 1);
    }
    __syncthreads();
    bhist[blockIdx.x * 512 + t] = lh[t];
    bhist[blockIdx.x * 512 + t + 256] = lh[t + 256];
    if (lh[t]) atomicAdd(&btot[t], lh[t]);
    if (t + 256 < NB && lh[t + 256]) atomicAdd(&btot[t + 256], lh[t + 256]);
}

__global__ __launch_bounds__(256)
void k_bscan(const int* __restrict__ btot, int* __restrict__ bbase,
             int* __restrict__ bcur, int NB, int E) {
    __shared__ int s[512];
    int t = threadIdx.x;
    int v0 = (t < NB) ? btot[t] : 0;
    int v1 = (t + 256 < NB) ? btot[t + 256] : 0;
    s[t] = v0; s[t + 256] = v1;
    __syncthreads();
    for (int st = 1; st < 512; st <<= 1) {
        int a0 = (t >= st) ? s[t - st] : 0;
        int a1 = (t + 256 >= st) ? s[t + 256 - st] : 0;
        __syncthreads();
        s[t] += a0; s[t + 256] += a1;
        __syncthreads();
    }
    if (t < NB)       { bbase[t] = s[t] - v0;             bcur[t] = s[t] - v0; }
    if (t + 256 < NB) { bbase[t + 256] = s[t + 256] - v1; bcur[t + 256] = s[t + 256] - v1; }
    if (t == 0) bbase[NB] = E;
}

__global__ __launch_bounds__(256)
void k_bscatter(const int* __restrict__ ei, int* __restrict__ bcur,
                const int* __restrict__ bhist,
                int2* __restrict__ pairs, int E, int NB) {
    __shared__ int2 sp[CH];                   // 32 KB staging
    __shared__ int lh[512], lsc[512], lcur[512], gb[512];
    int t = threadIdx.x;
    lh[t] = bhist[blockIdx.x * 512 + t];
    lh[t + 256] = bhist[blockIdx.x * 512 + t + 256];
    lcur[t] = 0; lcur[t + 256] = 0;
    __syncthreads();
    lsc[t] = lh[t]; lsc[t + 256] = lh[t + 256];
    __syncthreads();
    for (int st = 1; st < 512; st <<= 1) {
        int a0 = (t >= st) ? lsc[t - st] : 0;
        int a1 = (t + 256 >= st) ? lsc[t + 256 - st] : 0;
        __syncthreads();
        lsc[t] += a0; lsc[t + 256] += a1;
        __syncthreads();
    }
    int base = blockIdx.x * CH;
    for (int i = t; i < CH; i += 256) {
        int e = base + i;
        if (e < E) {
            int s = ei[e], d = ei[E + e];
            int b = d >> BSHIFT;
            int pos = lsc[b] - lh[b] + atomicAdd(&lcur[b], 1);
            sp[pos] = make_int2(s, d);
        }
    }
    __syncthreads();
    if (t < NB && lh[t]) gb[t] = atomicAdd(&bcur[t], lh[t]);
    if (t + 256 < NB && lh[t + 256]) gb[t + 256] = atomicAdd(&bcur[t + 256], lh[t + 256]);
    __syncthreads();
    int tot = lsc[511];
    for (int i = t; i < tot; i += 256) {
        int2 p = sp[i];
        int b = p.y >> BSHIFT;
        pairs[gb[b] + (i - (lsc[b] - lh[b]))] = p;
    }
}

__global__ __launch_bounds__(256)
void k_bcsr(const int2* __restrict__ pairs, const int* __restrict__ bbase,
            int* __restrict__ csr, int* __restrict__ off, int N, int NB, int E) {
    __shared__ int2 sp[BCAP];
    __shared__ int lh[256], lsc[256], lcur[256];
    int t = threadIdx.x;
    int b = blockIdx.x;
    int base = bbase[b];
    int m = bbase[b + 1] - base;
    int v0 = b << BSHIFT;
    lh[t] = 0; lcur[t] = 0;
    __syncthreads();
    bool fits = (m <= BCAP);
    for (int i = t; i < m; i += 256) {
        int2 p = pairs[base + i];
        if (fits) sp[i] = p;
        atomicAdd(&lh[p.y & 255], 1);
    }
    __syncthreads();
    int myv = lh[t];
    lsc[t] = myv;
    __syncthreads();
    for (int st = 1; st < 256; st <<= 1) {
        int a = (t >= st) ? lsc[t - st] : 0;
        __syncthreads();
        lsc[t] += a;
        __syncthreads();
    }
    int excl = lsc[t] - myv;
    __syncthreads();
    lsc[t] = excl;
    __syncthreads();
    int v = v0 + t;
    if (v < N) off[v] = base + excl;
    if (b == NB - 1 && t == 0) off[N] = E;
    for (int i = t; i < m; i += 256) {
        int2 p = fits ? sp[i] : pairs[base + i];
        int d = p.y & 255;
        int pos = lsc[d] + atomicAdd(&lcur[d], 1);
        csr[base + pos] = p.x;
    }
}

// ---------------- Prep: fragment-packed weights (bf16 hi/lo) ----------------
// b=0: mlp W1   b=1: mlp g*W2   b=2: k12   b=3..5: sage layer b-3

__global__ void k_prep(const float* __restrict__ mW1, const float* __restrict__ mg,
                       const float* __restrict__ mbn, const float* __restrict__ mW2,
                       const float* __restrict__ mb2,
                       const float* __restrict__ Wl, const float* __restrict__ Wr,
                       unsigned short* __restrict__ w1fh, unsigned short* __restrict__ w1fl,
                       unsigned short* __restrict__ w2fh, unsigned short* __restrict__ w2fl,
                       unsigned short* __restrict__ wsfh, unsigned short* __restrict__ wsfl,
                       float* __restrict__ k12)
{
    int b = blockIdx.x, t = threadIdx.x;
    if (b == 0) {
        for (int idx = t; idx < 2048; idx += 256) {
            int nt = idx >> 7, rem = idx & 127;
            int kc = rem >> 6, ln = rem & 63;
#pragma unroll
            for (int i = 0; i < 8; ++i) {
                int c = kc * 32 + (ln >> 4) * 8 + i;
                int j = nt * 16 + (ln & 15);
                float v = mW1[c * 256 + j];
                unsigned short hi = f2bh(v);
                w1fh[idx * 8 + i] = hi;
                w1fl[idx * 8 + i] = f2bh(v - bh2f(hi));
            }
        }
    } else if (b == 1) {
        for (int idx = t; idx < 2048; idx += 256) {
            int nt2 = idx >> 9, rem = idx & 511;
            int kc2 = rem >> 6, ln = rem & 63;
#pragma unroll
            for (int i = 0; i < 8; ++i) {
                int j = kc2 * 32 + (ln >> 4) * 8 + i;
                int o = nt2 * 16 + (ln & 15);
                float v = mg[j] * mW2[j * 64 + o];
                unsigned short hi = f2bh(v);
                w2fh[idx * 8 + i] = hi;
                w2fl[idx * 8 + i] = f2bh(v - bh2f(hi));
            }
        }
    } else if (b == 2 && t < 64) {
        float a1 = 0.f, a2 = 0.f;
        for (int j = 0; j < 256; ++j) {
            a1 += mbn[j] * mW2[j * 64 + t];
            a2 += mg[j]  * mW2[j * 64 + t];
        }
        k12[t] = a1 + mb2[t];
        k12[64 + t] = a2;
    } else if (b >= 3 && b < 6) {
        int l = b - 3;
        for (int idx = t; idx < 1536; idx += 256) {
            int tile = idx >> 6, ln = idx & 63;
            int nt = tile / 6, kc = tile % 6;
#pragma unroll
            for (int i = 0; i < 8; ++i) {
                int k = kc * 32 + (ln >> 4) * 8 + i;
                int o = nt * 16 + (ln & 15);
                float v = (k < 128) ? Wl[((l * 128) + k) * 64 + o]
                                    : Wr[((l * 64) + (k - 128)) * 64 + o];
                unsigned short hi = f2bh(v);
                wsfh[((l * 24 + tile) * 64 + ln) * 8 + i] = hi;
                wsfl[((l * 24 + tile) * 64 + ln) * 8 + i] = f2bh(v - bh2f(hi));
            }
        }
    }
}

// ---------------- Layer 0 (N_IN=4), one thread per node, 8-deep batches ----------------

__global__ __launch_bounds__(256, 4)
void k_layer0(const float* __restrict__ x, float* __restrict__ hout,
              const int* __restrict__ off, const int* __restrict__ csr,
              const float* __restrict__ Wl0, const float* __restrict__ bl0,
              const float* __restrict__ Wr0, const float* __restrict__ Wres,
              const float* __restrict__ bres, const float* __restrict__ lg,
              const float* __restrict__ lb, int N)
{
    __shared__ float sWl[512], sWr[256], sWres[256], sC[256];
    int t = threadIdx.x;
    sWl[t] = Wl0[t]; sWl[256 + t] = Wl0[256 + t];
    sWr[t] = Wr0[t];
    sWres[t] = Wres[t];
    if (t < 64) { sC[t] = bl0[t]; sC[64 + t] = bres[t]; sC[128 + t] = lg[t]; sC[192 + t] = lb[t]; }
    __syncthreads();
    int v = blockIdx.x * 256 + t;
    if (v >= N) return;
    const float4* X4 = reinterpret_cast<const float4*>(x);
    float4 xv = X4[v];
    int s0 = off[v], s1 = off[v + 1];
    int deg = s1 - s0;
    float4 mx = {NEG_INF, NEG_INF, NEG_INF, NEG_INF};
    float4 sm = {0.f, 0.f, 0.f, 0.f};
    for (int e = s0; e < s1; e += 8) {
        int last = s1 - 1;
        float4 a[8];
#pragma unroll
        for (int u = 0; u < 8; ++u) a[u] = X4[csr[min(e + u, last)]];
#pragma unroll
        for (int u = 0; u < 8; ++u) {
            mx.x = fmaxf(mx.x, a[u].x); mx.y = fmaxf(mx.y, a[u].y);
            mx.z = fmaxf(mx.z, a[u].z); mx.w = fmaxf(mx.w, a[u].w);
            sm.x += a[u].x; sm.y += a[u].y; sm.z += a[u].z; sm.w += a[u].w;
        }
    }
    float4 mn;
    if (deg == 0) {
        mx.x = 0.f; mx.y = 0.f; mx.z = 0.f; mx.w = 0.f;
        mn.x = 0.f; mn.y = 0.f; mn.z = 0.f; mn.w = 0.f;
    } else {
        int npad = (((deg + 7) >> 3) << 3) - deg;        // dups all clamp to csr[s1-1]
        float4 xl = X4[csr[s1 - 1]];                      // L1-hot
        float fp = (float)npad, inv = 1.f / (float)deg;
        mn.x = (sm.x - fp * xl.x) * inv; mn.y = (sm.y - fp * xl.y) * inv;
        mn.z = (sm.z - fp * xl.z) * inv; mn.w = (sm.w - fp * xl.w) * inv;
    }
    float a[64];
    float acc1 = 0.f, acc2 = 0.f;
#pragma unroll
    for (int k = 0; k < 64; ++k) {
        float tv = sC[k]
            + mx.x * sWl[k]       + mx.y * sWl[64 + k]  + mx.z * sWl[128 + k] + mx.w * sWl[192 + k]
            + mn.x * sWl[256 + k] + mn.y * sWl[320 + k] + mn.z * sWl[384 + k] + mn.w * sWl[448 + k]
            + xv.x * sWr[k]       + xv.y * sWr[64 + k]  + xv.z * sWr[128 + k] + xv.w * sWr[192 + k];
        a[k] = tv; acc1 += tv; acc2 += tv * tv;
    }
    float mu = acc1 * (1.f / 64.f);
    float var = acc2 * (1.f / 64.f) - mu * mu;
    float rs = rsqrtf(var + 1e-5f);
    float* orow = hout + (size_t)v * 64;
#pragma unroll
    for (int k = 0; k < 64; ++k) {
        float res = sC[64 + k] + xv.x * sWres[k] + xv.y * sWres[64 + k]
                  + xv.z * sWres[128 + k] + xv.w * sWres[192 + k];
        float y = (a[k] - mu) * rs * sC[128 + k] + sC[192 + k] + res;
        orow[k] = silu_f(y);
    }
}

// ---------------- k_agg: gather + aggregate (round-10 structure; at plateau) ----------------

__global__ __launch_bounds__(256, 8)
void k_agg(const float* __restrict__ hin, float* __restrict__ aggws,
           const int* __restrict__ off, const int* __restrict__ csr, int N)
{
    int lane = threadIdx.x & 63;
    int gw = (blockIdx.x * blockDim.x + threadIdx.x) >> 6;
    int nw = (gridDim.x * blockDim.x) >> 6;
    for (int v = gw; v < N; v += nw) {
        int s0 = off[v], s1 = off[v + 1];
        int deg = s1 - s0;
        float mx = NEG_INF, sm = 0.f;
        int npad = 0;
        for (int cb = s0; cb < s1; cb += 64) {
            int cdeg = min(64, s1 - cb);
            int idxv = csr[min(cb + lane, s1 - 1)];
            for (int b = 0; b < cdeg; b += 16) {
                float vv[16];
#pragma unroll
                for (int u = 0; u < 16; ++u) {
                    int iu = __builtin_amdgcn_readlane(idxv, b + u);  // b+u <= 63
                    vv[u] = hin[((size_t)iu << 6) + lane];
                }
#pragma unroll
                for (int u = 0; u < 16; ++u) { mx = fmaxf(mx, vv[u]); sm += vv[u]; }
            }
            npad += (((cdeg + 15) >> 4) << 4) - cdeg;   // dup lanes all clamp to csr[s1-1]
        }
        float mean;
        if (deg == 0) { mx = 0.f; mean = 0.f; }
        else {
            float hl = hin[((size_t)csr[s1 - 1] << 6) + lane];   // L1-hot
            mean = (sm - (float)npad * hl) / (float)deg;
        }
        aggws[((size_t)v << 7) + lane] = mx;
        aggws[((size_t)v << 7) + 64 + lane] = mean;
    }
}

// ---------------- k_smm_d: LDS-free MFMA SAGE matmul+LN+silu (layers 1-2) ----------------

__global__ __launch_bounds__(256, 4)
void k_smm_d(const float* __restrict__ aggws, const float* __restrict__ hin,
             float* __restrict__ hout,
             const unsigned short* __restrict__ wfh, const unsigned short* __restrict__ wfl,
             const float* __restrict__ bl, const float* __restrict__ lg,
             const float* __restrict__ lb, int N)
{
    int t = threadIdx.x;
    int lane = t & 63, w = t >> 6, quad = lane >> 4, l15 = lane & 15;
    int nodebase = (blockIdx.x * 4 + w) * 16;
    if (nodebase >= N) return;
    int arow = min(nodebase + l15, N - 1);

    short8 ah[6], al[6];
#pragma unroll
    for (int kc = 0; kc < 6; ++kc) {
        const float* src = (kc < 4)
            ? (aggws + ((size_t)arow << 7) + kc * 32 + quad * 8)
            : (hin + ((size_t)arow << 6) + (kc - 4) * 32 + quad * 8);
        float4 f0 = *(const float4*)(src);
        float4 f1 = *(const float4*)(src + 4);
        float vv[8] = {f0.x, f0.y, f0.z, f0.w, f1.x, f1.y, f1.z, f1.w};
#pragma unroll
        for (int i = 0; i < 8; ++i) {
            unsigned short hi = f2bh(vv[i]);
            ah[kc][i] = (short)hi;
            al[kc][i] = (short)f2bh(vv[i] - bh2f(hi));
        }
    }

    f32x4 acc[4];
#pragma unroll
    for (int nt = 0; nt < 4; ++nt) acc[nt] = (f32x4){0.f, 0.f, 0.f, 0.f};
#pragma unroll
    for (int kc = 0; kc < 6; ++kc) {
#pragma unroll
        for (int nt = 0; nt < 4; ++nt) {
            int fo = ((nt * 6 + kc) * 64 + lane) * 8;
            short8 bh_ = *(const short8*)(wfh + fo);
            short8 bl_ = *(const short8*)(wfl + fo);
            acc[nt] = __builtin_amdgcn_mfma_f32_16x16x32_bf16(ah[kc], bh_, acc[nt], 0, 0, 0);
            acc[nt] = __builtin_amdgcn_mfma_f32_16x16x32_bf16(al[kc], bh_, acc[nt], 0, 0, 0);
            acc[nt] = __builtin_amdgcn_mfma_f32_16x16x32_bf16(ah[kc], bl_, acc[nt], 0, 0, 0);
        }
    }

    float blv[4], gv[4], bv[4];
#pragma unroll
    for (int nt = 0; nt < 4; ++nt) {
        int ch = nt * 16 + l15;
        blv[nt] = bl[ch]; gv[nt] = lg[ch]; bv[nt] = lb[ch];
    }
    float ps[4], pq[4];
#pragma unroll
    for (int r = 0; r < 4; ++r) { ps[r] = 0.f; pq[r] = 0.f; }
#pragma unroll
    for (int nt = 0; nt < 4; ++nt)
#pragma unroll
        for (int r = 0; r < 4; ++r) {
            float tv = acc[nt][r] + blv[nt];
            acc[nt][r] = tv;
            ps[r] += tv; pq[r] += tv * tv;
        }
#pragma unroll
    for (int r = 0; r < 4; ++r) {
        float a = ps[r], b = pq[r];
#pragma unroll
        for (int m = 1; m < 16; m <<= 1) {
            a += __shfl_xor(a, m, 64);
            b += __shfl_xor(b, m, 64);
        }
        ps[r] = a; pq[r] = b;
    }
#pragma unroll
    for (int r = 0; r < 4; ++r) {
        int node = nodebase + quad * 4 + r;
        float mu = ps[r] * (1.f / 64.f);
        float var = pq[r] * (1.f / 64.f) - mu * mu;
        float rs = rsqrtf(var + 1e-5f);
        if (node < N) {
#pragma unroll
            for (int nt = 0; nt < 4; ++nt) {
                float hs = hin[(size_t)node * 64 + nt * 16 + l15];   // L2-hot
                float y = (acc[nt][r] - mu) * rs * gv[nt] + bv[nt] + hs;
                hout[(size_t)node * 64 + nt * 16 + l15] = silu_f(y);
            }
        }
    }
}

// ---------------- k_sagemlp: fused SAGE layer-3 + MLP ----------------
// Phase A = smm_d (GEMM K=192 + quad-LN + residual + silu), output written as
// bf16 hi/lo directly into the MLP's LDS staging (skips the 102 MB hb round
// trip). Phase B = k_mlpm from GEMM1 onward, verbatim.

__global__ __launch_bounds__(256, 2)
void k_sagemlp(const float* __restrict__ aggws, const float* __restrict__ hin,
               float* __restrict__ hout,
               const unsigned short* __restrict__ wfh, const unsigned short* __restrict__ wfl,
               const float* __restrict__ bls, const float* __restrict__ lgs,
               const float* __restrict__ lbs,
               const unsigned short* __restrict__ w1fh, const unsigned short* __restrict__ w1fl,
               const unsigned short* __restrict__ w2fh, const unsigned short* __restrict__ w2fl,
               const float* __restrict__ b1, const float* __restrict__ K12, int N)
{
    __shared__ __align__(16) char lds[70656];
    float* p1 = (float*)lds;
    float* p2 = (float*)(lds + 1024);
    unsigned short* hhi = (unsigned short*)(lds + 2048);   // [64][72] (phase A out)
    unsigned short* hlo = (unsigned short*)(lds + 11264);
    unsigned int* spack = (unsigned int*)(lds + 2048);     // phase B repack (after GEMM1)

    int t = threadIdx.x;
    int lane = t & 63, w = t >> 6, quad = lane >> 4, l15 = lane & 15;

    // ======== Phase A: SAGE layer-3 ========
    {
        int nodebase = blockIdx.x * 64 + w * 16;
        int arow = min(nodebase + l15, N - 1);             // clamp; no early return (barriers)
        short8 ah[6], al[6];
#pragma unroll
        for (int kc = 0; kc < 6; ++kc) {
            const float* src = (kc < 4)
                ? (aggws + ((size_t)arow << 7) + kc * 32 + quad * 8)
                : (hin + ((size_t)arow << 6) + (kc - 4) * 32 + quad * 8);
            float4 f0 = *(const float4*)(src);
            float4 f1 = *(const float4*)(src + 4);
            float vv[8] = {f0.x, f0.y, f0.z, f0.w, f1.x, f1.y, f1.z, f1.w};
#pragma unroll
            for (int i = 0; i < 8; ++i) {
                unsigned short hi = f2bh(vv[i]);
                ah[kc][i] = (short)hi;
                al[kc][i] = (short)f2bh(vv[i] - bh2f(hi));
            }
        }
        f32x4 sacc[4];
#pragma unroll
        for (int nt = 0; nt < 4; ++nt) sacc[nt] = (f32x4){0.f, 0.f, 0.f, 0.f};
#pragma unroll
        for (int kc = 0; kc < 6; ++kc) {
#pragma unroll
            for (int nt = 0; nt < 4; ++nt) {
                int fo = ((nt * 6 + kc) * 64 + lane) * 8;
                short8 bh_ = *(const short8*)(wfh + fo);
                short8 bl_ = *(const short8*)(wfl + fo);
                sacc[nt] = __builtin_amdgcn_mfma_f32_16x16x32_bf16(ah[kc], bh_, sacc[nt], 0, 0, 0);
                sacc[nt] = __builtin_amdgcn_mfma_f32_16x16x32_bf16(al[kc], bh_, sacc[nt], 0, 0, 0);
                sacc[nt] = __builtin_amdgcn_mfma_f32_16x16x32_bf16(ah[kc], bl_, sacc[nt], 0, 0, 0);
            }
        }
        float blv[4], gv[4], bv[4];
#pragma unroll
        for (int nt = 0; nt < 4; ++nt) {
            int ch = nt * 16 + l15;
            blv[nt] = bls[ch]; gv[nt] = lgs[ch]; bv[nt] = lbs[ch];
        }
        float ps[4], pq[4];
#pragma unroll
        for (int r = 0; r < 4; ++r) { ps[r] = 0.f; pq[r] = 0.f; }
#pragma unroll
        for (int nt = 0; nt < 4; ++nt)
#pragma unroll
            for (int r = 0; r < 4; ++r) {
                float tv = sacc[nt][r] + blv[nt];
                sacc[nt][r] = tv;
                ps[r] += tv; pq[r] += tv * tv;
            }
#pragma unroll
        for (int r = 0; r < 4; ++r) {
            float a = ps[r], b = pq[r];
#pragma unroll
            for (int m = 1; m < 16; m <<= 1) {
                a += __shfl_xor(a, m, 64);
                b += __shfl_xor(b, m, 64);
            }
            ps[r] = a; pq[r] = b;
        }
        // LN + residual + silu -> bf16 hi/lo into MLP staging (C-layout -> [node][ch])
#pragma unroll
        for (int r = 0; r < 4; ++r) {
            int nl = w * 16 + quad * 4 + r;                // node_local in [0,64)
            int nclamp = min(blockIdx.x * 64 + nl, N - 1);
            float mu = ps[r] * (1.f / 64.f);
            float var = pq[r] * (1.f / 64.f) - mu * mu;
            float rs = rsqrtf(var + 1e-5f);
#pragma unroll
            for (int nt = 0; nt < 4; ++nt) {
                float hs = hin[(size_t)nclamp * 64 + nt * 16 + l15];   // L2-hot
                float sv = silu_f((sacc[nt][r] - mu) * rs * gv[nt] + bv[nt] + hs);
                unsigned short hi = f2bh(sv);
                int idx = nl * 72 + nt * 16 + l15;
                hhi[idx] = hi;
                hlo[idx] = f2bh(sv - bh2f(hi));
            }
        }
    }
    __syncthreads();

    // ======== Phase B: MLP (k_mlpm from GEMM1 onward) ========
    f32x4 acc[4][4];
#pragma unroll
    for (int mt = 0; mt < 4; ++mt)
#pragma unroll
        for (int nt = 0; nt < 4; ++nt)
            acc[mt][nt] = (f32x4){0.f, 0.f, 0.f, 0.f};
#pragma unroll
    for (int kc = 0; kc < 2; ++kc) {
        short8 ah[4], al[4];
#pragma unroll
        for (int mt = 0; mt < 4; ++mt) {
            int idx = (mt * 16 + l15) * 72 + kc * 32 + quad * 8;
            ah[mt] = *(const short8*)(hhi + idx);
            al[mt] = *(const short8*)(hlo + idx);
        }
#pragma unroll
        for (int nt = 0; nt < 4; ++nt) {
            int fo = (((w * 4 + nt) * 2 + kc) * 64 + lane) * 8;
            short8 bh_ = *(const short8*)(w1fh + fo);
            short8 bl_ = *(const short8*)(w1fl + fo);
#pragma unroll
            for (int mt = 0; mt < 4; ++mt) {
                acc[mt][nt] = __builtin_amdgcn_mfma_f32_16x16x32_bf16(ah[mt], bh_, acc[mt][nt], 0, 0, 0);
                acc[mt][nt] = __builtin_amdgcn_mfma_f32_16x16x32_bf16(al[mt], bh_, acc[mt][nt], 0, 0, 0);
                acc[mt][nt] = __builtin_amdgcn_mfma_f32_16x16x32_bf16(ah[mt], bl_, acc[mt][nt], 0, 0, 0);
            }
        }
    }

    float b1v[4];
#pragma unroll
    for (int nt = 0; nt < 4; ++nt) b1v[nt] = b1[(w * 4 + nt) * 16 + l15];
    float psum[4][4], psq[4][4];
#pragma unroll
    for (int mt = 0; mt < 4; ++mt)
#pragma unroll
        for (int r = 0; r < 4; ++r) { psum[mt][r] = 0.f; psq[mt][r] = 0.f; }
#pragma unroll
    for (int mt = 0; mt < 4; ++mt)
#pragma unroll
        for (int nt = 0; nt < 4; ++nt)
#pragma unroll
            for (int r = 0; r < 4; ++r) {
                float sv = silu_f(acc[mt][nt][r] + b1v[nt]);
                acc[mt][nt][r] = sv;
                psum[mt][r] += sv;
                psq[mt][r] += sv * sv;
            }
#pragma unroll
    for (int mt = 0; mt < 4; ++mt)
#pragma unroll
        for (int r = 0; r < 4; ++r) {
            float a = psum[mt][r], b = psq[mt][r];
#pragma unroll
            for (int m = 1; m < 16; m <<= 1) {
                a += __shfl_xor(a, m, 64);
                b += __shfl_xor(b, m, 64);
            }
            psum[mt][r] = a; psq[mt][r] = b;
        }
    if (l15 == 0) {
#pragma unroll
        for (int mt = 0; mt < 4; ++mt)
#pragma unroll
            for (int r = 0; r < 4; ++r) {
                int nl = mt * 16 + quad * 4 + r;
                p1[w * 64 + nl] = psum[mt][r];
                p2[w * 64 + nl] = psq[mt][r];
            }
    }
    __syncthreads();   // all GEMM1 hhi/hlo reads done; partials visible

#pragma unroll
    for (int mt = 0; mt < 4; ++mt)
#pragma unroll
        for (int nt = 0; nt < 4; ++nt)
#pragma unroll
            for (int r = 0; r < 4; ++r) {
                float sv = acc[mt][nt][r];
                unsigned short hi = f2bh(sv);
                unsigned short lo = f2bh(sv - bh2f(hi));
                spack[(mt * 16 + quad * 4 + r) * 268 + (w * 4 + nt) * 16 + l15] =
                    (((unsigned int)hi) << 16) | (unsigned int)lo;
            }
    __syncthreads();

    f32x4 acc2[4];
#pragma unroll
    for (int nt2 = 0; nt2 < 4; ++nt2) acc2[nt2] = (f32x4){0.f, 0.f, 0.f, 0.f};
#pragma unroll
    for (int kc2 = 0; kc2 < 8; ++kc2) {
        int base = (w * 16 + l15) * 268 + kc2 * 32 + quad * 8;
        uint4 q0 = *(const uint4*)(spack + base);
        uint4 q1 = *(const uint4*)(spack + base + 4);
        unsigned int vv[8] = {q0.x, q0.y, q0.z, q0.w, q1.x, q1.y, q1.z, q1.w};
        short8 ah, al;
#pragma unroll
        for (int i = 0; i < 8; ++i) {
            ah[i] = (short)(vv[i] >> 16);
            al[i] = (short)(vv[i] & 0xffffu);
        }
#pragma unroll
        for (int nt2 = 0; nt2 < 4; ++nt2) {
            int fo = ((nt2 * 8 + kc2) * 64 + lane) * 8;
            short8 bh_ = *(const short8*)(w2fh + fo);
            short8 bl_ = *(const short8*)(w2fl + fo);
            acc2[nt2] = __builtin_amdgcn_mfma_f32_16x16x32_bf16(ah, bh_, acc2[nt2], 0, 0, 0);
            acc2[nt2] = __builtin_amdgcn_mfma_f32_16x16x32_bf16(al, bh_, acc2[nt2], 0, 0, 0);
            acc2[nt2] = __builtin_amdgcn_mfma_f32_16x16x32_bf16(ah, bl_, acc2[nt2], 0, 0, 0);
        }
    }

    float k1v[4], k2v[4];
#pragma unroll
    for (int nt2 = 0; nt2 < 4; ++nt2) {
        k1v[nt2] = K12[nt2 * 16 + l15];
        k2v[nt2] = K12[64 + nt2 * 16 + l15];
    }
#pragma unroll
    for (int r = 0; r < 4; ++r) {
        int nl = w * 16 + quad * 4 + r;
        float s1 = p1[nl] + p1[64 + nl] + p1[128 + nl] + p1[192 + nl];
        float s2 = p2[nl] + p2[64 + nl] + p2[128 + nl] + p2[192 + nl];
        float mu = s1 * (1.f / 256.f);
        float var = s2 * (1.f / 256.f) - mu * mu;
        float rs = rsqrtf(var + 1e-5f);
        float rm = rs * mu;
        int node = blockIdx.x * 64 + nl;
        if (node < N) {
#pragma unroll
            for (int nt2 = 0; nt2 < 4; ++nt2)
                hout[(size_t)node * 64 + nt2 * 16 + l15] =
                    rs * acc2[nt2][r] + k1v[nt2] - rm * k2v[nt2];
        }
    }
}

// ---------------- Readout: block per graph ----------------

__global__ __launch_bounds__(256, 2)
void k_readout(const float* __restrict__ h2, const float* __restrict__ x,
               const int* __restrict__ ptr,
               const float* __restrict__ W1, const float* __restrict__ b1,
               const float* __restrict__ lg, const float* __restrict__ lb,
               const float* __restrict__ W2, const float* __restrict__ b2,
               float* __restrict__ out)
{
    __shared__ float f[196];
    __shared__ float sred[4][64];
    __shared__ float mred[4][64];
    __shared__ float lred[8];
    __shared__ float pr[4][4];
    int t = threadIdx.x, lane = t & 63, w = t >> 6;
    int g = blockIdx.x;
    int s0 = ptr[g], s1 = ptr[g + 1];
    float sm = 0.f, mx = NEG_INF;
    for (int r = s0 + w; r < s1; r += 4) {
        float v = h2[(size_t)r * 64 + lane];
        sm += v; mx = fmaxf(mx, v);
    }
    sred[w][lane] = sm; mred[w][lane] = mx;
    __syncthreads();
    if (w == 0) {
        float ssum = sred[0][lane] + sred[1][lane] + sred[2][lane] + sred[3][lane];
        float smax = fmaxf(fmaxf(mred[0][lane], mred[1][lane]),
                           fmaxf(mred[2][lane], mred[3][lane]));
        int cnt = s1 - s0;
        if (cnt == 0) smax = 0.f;
        f[lane] = ssum / (float)max(cnt, 1);
        f[64 + lane] = smax;
        f[128 + lane] = ssum;
    }
    if (t < 4) f[192 + t] = x[(size_t)s0 * 4 + t];
    __syncthreads();
    float o = b1[t];
    for (int c = 0; c < 196; ++c) o += f[c] * W1[c * 256 + t];
    o = silu_f(o);
    float s = o, s2v = o * o;
#pragma unroll
    for (int m = 1; m < 64; m <<= 1) { s += __shfl_xor(s, m, 64); s2v += __shfl_xor(s2v, m, 64); }
    if (lane == 0) { lred[w] = s; lred[4 + w] = s2v; }
    __syncthreads();
    float tot = lred[0] + lred[1] + lred[2] + lred[3];
    float tot2 = lred[4] + lred[5] + lred[6] + lred[7];
    float mu = tot * (1.f / 256.f);
    float var = tot2 * (1.f / 256.f) - mu * mu;
    float u = (o - mu) * rsqrtf(var + 1e-5f) * lg[t] + lb[t];
    float4 w2r = reinterpret_cast<const float4*>(W2)[t];
    float p0 = u * w2r.x, p1 = u * w2r.y, p2 = u * w2r.z, p3 = u * w2r.w;
#pragma unroll
    for (int m = 1; m < 64; m <<= 1) {
        p0 += __shfl_xor(p0, m, 64); p1 += __shfl_xor(p1, m, 64);
        p2 += __shfl_xor(p2, m, 64); p3 += __shfl_xor(p3, m, 64);
    }
    if (lane == 0) { pr[w][0] = p0; pr[w][1] = p1; pr[w][2] = p2; pr[w][3] = p3; }
    __syncthreads();
    if (t < 4) out[g * 4 + t] = pr[0][t] + pr[1][t] + pr[2][t] + pr[3][t] + b2[t];
}

// ---------------- launch ----------------

extern "C" void kernel_launch(void* const* d_in, const int* in_sizes, int n_in,
                              void* d_out, int out_size, void* d_ws, size_t ws_size,
                              hipStream_t stream)
{
    const float* x    = (const float*)d_in[0];
    const int*   ei   = (const int*)d_in[1];
    const int*   ptr  = (const int*)d_in[3];
    const float* Wl0  = (const float*)d_in[4];
    const float* bl0  = (const float*)d_in[5];
    const float* Wr0  = (const float*)d_in[6];
    const float* Wl   = (const float*)d_in[7];
    const float* bl   = (const float*)d_in[8];
    const float* Wr   = (const float*)d_in[9];
    const float* Wres = (const float*)d_in[10];
    const float* bres = (const float*)d_in[11];
    const float* lng  = (const float*)d_in[12];
    const float* lnb  = (const float*)d_in[13];
    const float* mW1  = (const float*)d_in[14];
    const float* mb1  = (const float*)d_in[15];
    const float* mg   = (const float*)d_in[16];
    const float* mbn  = (const float*)d_in[17];
    const float* mW2  = (const float*)d_in[18];
    const float* mb2  = (const float*)d_in[19];
    const float* rW1  = (const float*)d_in[20];
    const float* rb1  = (const float*)d_in[21];
    const float* rg   = (const float*)d_in[22];
    const float* rbn  = (const float*)d_in[23];
    const float* rW2  = (const float*)d_in[24];
    const float* rb2  = (const float*)d_in[25];
    float* out = (float*)d_out;

    int N = in_sizes[0] / 4;
    int E = in_sizes[1] / 2;
    int NG = in_sizes[3] - 1;
    int nchunk = (N + 255) / 256;
    int nblkm  = (N + 63) / 64;
    int NB     = (N + 255) >> BSHIFT;
    int nbh    = (E + CH - 1) / CH;

    char* ws = (char*)d_ws;
    size_t o = 0;
    auto alloc = [&](size_t bytes) -> void* {
        void* p = ws + o;
        o += (bytes + 255) & ~(size_t)255;
        return p;
    };
    int*   off   = (int*)alloc((size_t)(N + 1) * 4);
    int*   btot  = (int*)alloc((size_t)NB * 4);
    int*   bbase = (int*)alloc((size_t)(NB + 1) * 4);
    int*   bcur  = (int*)alloc((size_t)NB * 4);
    int*   bhist = (int*)alloc((size_t)nbh * 512 * 4);
    int*   csr   = (int*)alloc((size_t)E * 4);
    int2*  pairs = (int2*)alloc((size_t)E * 8);
    float* ha    = (float*)alloc((size_t)N * 64 * 4);
    float* hb    = (float*)alloc((size_t)N * 64 * 4);
    float* aggws = (float*)alloc((size_t)N * 128 * 4);
    unsigned short* w1fh = (unsigned short*)alloc(16384 * 2);
    unsigned short* w1fl = (unsigned short*)alloc(16384 * 2);
    unsigned short* w2fh = (unsigned short*)alloc(16384 * 2);
    unsigned short* w2fl = (unsigned short*)alloc(16384 * 2);
    unsigned short* wsfh = (unsigned short*)alloc(36864 * 2);
    unsigned short* wsfl = (unsigned short*)alloc(36864 * 2);
    float* k12   = (float*)alloc(128 * 4);

    hipMemsetAsync(btot, 0, (size_t)NB * 4, stream);
    k_prep<<<6, 256, 0, stream>>>(mW1, mg, mbn, mW2, mb2, Wl, Wr,
                                  w1fh, w1fl, w2fh, w2fl, wsfh, wsfl, k12);
    k_bhist<<<nbh, 256, 0, stream>>>(ei, btot, bhist, E, NB);
    k_bscan<<<1, 256, 0, stream>>>(btot, bbase, bcur, NB, E);
    k_bscatter<<<nbh, 256, 0, stream>>>(ei, bcur, bhist, pairs, E, NB);
    k_bcsr<<<NB, 256, 0, stream>>>(pairs, bbase, csr, off, N, NB, E);

    k_layer0<<<nchunk, 256, 0, stream>>>(x, ha, off, csr, Wl0, bl0, Wr0, Wres, bres, lng, lnb, N);

    k_agg<<<2048, 256, 0, stream>>>(ha, aggws, off, csr, N);
    k_smm_d<<<nblkm, 256, 0, stream>>>(aggws, ha, hb, wsfh,               wsfl,               bl,       lng + 64,  lnb + 64,  N);
    k_agg<<<2048, 256, 0, stream>>>(hb, aggws, off, csr, N);
    k_smm_d<<<nblkm, 256, 0, stream>>>(aggws, hb, ha, wsfh + 24 * 64 * 8, wsfl + 24 * 64 * 8, bl + 64,  lng + 128, lnb + 128, N);
    k_agg<<<2048, 256, 0, stream>>>(ha, aggws, off, csr, N);

    // fused: SAGE layer-3 + MLP (was k_smm_d -> hb, then k_mlpm hb -> ha)
    k_sagemlp<<<nblkm, 256, 0, stream>>>(aggws, ha, hb,
                                         wsfh + 48 * 64 * 8, wsfl + 48 * 64 * 8,
                                         bl + 128, lng + 192, lnb + 192,
                                         w1fh, w1fl, w2fh, w2fl, mb1, k12, N);
    k_readout<<<NG, 256, 0, stream>>>(hb, x, ptr, rW1, rb1, rg, rbn, rW2, rb2, out);
}